// Round 1
// 3943.756 us; speedup vs baseline: 2.9796x; 2.9796x over previous
//
#include <hip/hip_runtime.h>
#include <math.h>

#define BD 2
#define SD 1024
#define DDIM 1024
#define HH 16
#define LL 9
#define WW 1024
#define PP 128
#define VV 256
#define NN (BD*SD)

typedef __attribute__((ext_vector_type(8))) short short8;
typedef __attribute__((ext_vector_type(4))) float f32x4;

__device__ __forceinline__ float bf2f(unsigned int u) {
    return __uint_as_float((u & 0xffffu) << 16);
}
__device__ __forceinline__ unsigned short f2bf(float f) {
    unsigned int u = __float_as_uint(f);
    unsigned int r = (u + 0x7fffu + ((u >> 16) & 1u)) >> 16;
    return (unsigned short)r;
}

__device__ __forceinline__ float block_reduce_sum(float v, float* red) {
#pragma unroll
    for (int off = 32; off > 0; off >>= 1) v += __shfl_down(v, off);
    __syncthreads();
    if ((threadIdx.x & 63) == 0) red[threadIdx.x >> 6] = v;
    __syncthreads();
    return red[0] + red[1] + red[2] + red[3];
}

// ---------------- embed: x = byte_emb[tok] + pos_emb[s] (fp32) ----------------
__global__ __launch_bounds__(256) void embed_kernel(
    const int* __restrict__ seq, const float* __restrict__ bemb,
    const float* __restrict__ pemb, float* __restrict__ x)
{
    int i = blockIdx.x * 256 + threadIdx.x;
    if (i >= NN * DDIM) return;
    int n = i >> 10, d = i & 1023;
    int s = n & (SD - 1);
    int tok = seq[n];
    x[i] = bemb[tok * DDIM + d] + pemb[s * DDIM + d];
}

// ---------------- patch fp32 -> bf16 ----------------
__global__ __launch_bounds__(256) void cvt_bf16_kernel(
    const float* __restrict__ in, unsigned short* __restrict__ out, int n)
{
    int i = blockIdx.x * 256 + threadIdx.x;
    if (i < n) out[i] = f2bf(in[i]);
}

// ---------------- pidx = inclusive cumsum of patch_boundaries ----------------
__global__ void pidx_kernel(const int* __restrict__ pb, int* __restrict__ pidx)
{
    int b = threadIdx.x;
    if (b < BD) {
        int c = 0;
        for (int s = 0; s < SD; ++s) { c += pb[b * SD + s]; pidx[b * SD + s] = c; }
    }
}

// ---------------- LayerNorm: fp32 in -> bf16 out ----------------
__global__ __launch_bounds__(256) void ln_kernel(
    const float* __restrict__ x, const float* __restrict__ gg,
    const float* __restrict__ bb, unsigned short* __restrict__ out)
{
    __shared__ float red[4];
    const int row = blockIdx.x, tid = threadIdx.x;
    const float* xr = x + (size_t)row * DDIM;
    float v[4]; float s = 0.f, s2 = 0.f;
#pragma unroll
    for (int i = 0; i < 4; ++i) {
        float t = xr[tid + i * 256]; v[i] = t; s += t; s2 += t * t;
    }
    s = block_reduce_sum(s, red);
    __syncthreads();
    s2 = block_reduce_sum(s2, red);
    float mean = s * (1.f / DDIM);
    float var = s2 * (1.f / DDIM) - mean * mean;
    float rs = rsqrtf(var + 1e-5f);
    unsigned short* orow = out + (size_t)row * DDIM;
#pragma unroll
    for (int i = 0; i < 4; ++i) {
        int c = tid + i * 256;
        orow[c] = f2bf((v[i] - mean) * rs * gg[c] + bb[c]);
    }
}

// ---------------- GEMM: C[M,N] = A[M,K](bf16) @ B[N,K](fp32)^T + bias --------
// MODE 0: store fp32 to resid[M,N] (plain store)
// MODE 1: resid[M,N] (fp32) += val
// MODE 2: store bf16 gelu(val) to o0
// MODE 3: qkv scatter: which=col>>10 -> o{0,1,2}[((b*H+h)*seq+s)*64+d]
template<int MODE>
__global__ __launch_bounds__(256) void gemm_bt(
    const unsigned short* __restrict__ A, const float* __restrict__ B,
    const float* __restrict__ bias, float* __restrict__ resid,
    unsigned short* __restrict__ o0, unsigned short* __restrict__ o1,
    unsigned short* __restrict__ o2, int M, int N, int K, int seq)
{
    __shared__ __align__(16) unsigned short As[64 * 40];
    __shared__ __align__(16) unsigned short Bs[64 * 40];
    const int tid = threadIdx.x;
    const int m0 = blockIdx.y * 64, n0 = blockIdx.x * 64;
    const int w = tid >> 6, lane = tid & 63, quad = lane >> 4, mrow = lane & 15;
    f32x4 acc[4] = {{0,0,0,0},{0,0,0,0},{0,0,0,0},{0,0,0,0}};
    const int lr = tid >> 2, lc = (tid & 3) * 8;
    const uint4*  gA = (const uint4*)(A + (size_t)(m0 + lr) * K + lc);
    const float4* gB = (const float4*)(B + (size_t)(n0 + lr) * K + lc);

    for (int k0 = 0; k0 < K; k0 += 32) {
        __syncthreads();
        *(uint4*)&As[lr * 40 + lc] = gA[0];
        float4 b0 = gB[0], b1 = gB[1];
        short8 bv;
        bv[0] = (short)f2bf(b0.x); bv[1] = (short)f2bf(b0.y);
        bv[2] = (short)f2bf(b0.z); bv[3] = (short)f2bf(b0.w);
        bv[4] = (short)f2bf(b1.x); bv[5] = (short)f2bf(b1.y);
        bv[6] = (short)f2bf(b1.z); bv[7] = (short)f2bf(b1.w);
        *(short8*)&Bs[lr * 40 + lc] = bv;
        gA += 4; gB += 8;
        __syncthreads();
        short8 a = *(const short8*)&As[(w * 16 + mrow) * 40 + quad * 8];
#pragma unroll
        for (int t = 0; t < 4; ++t) {
            short8 bf = *(const short8*)&Bs[(t * 16 + mrow) * 40 + quad * 8];
            acc[t] = __builtin_amdgcn_mfma_f32_16x16x32_bf16(a, bf, acc[t], 0, 0, 0);
        }
    }

#pragma unroll
    for (int t = 0; t < 4; ++t) {
#pragma unroll
        for (int r = 0; r < 4; ++r) {
            int grow = m0 + w * 16 + quad * 4 + r;
            int gcol = n0 + t * 16 + mrow;
            float val = acc[t][r];
            if (bias) val += bias[gcol];
            if constexpr (MODE == 0) {
                resid[(size_t)grow * N + gcol] = val;
            } else if constexpr (MODE == 1) {
                resid[(size_t)grow * N + gcol] += val;
            } else if constexpr (MODE == 2) {
                float g = 0.5f * val * (1.0f + erff(val * 0.70710678118f));
                o0[(size_t)grow * N + gcol] = f2bf(g);
            } else {
                int which = gcol >> 10;
                int cD = gcol & 1023;
                int h = cD >> 6, d = cD & 63;
                int b = grow / seq, s = grow % seq;
                unsigned short* dst = (which == 0) ? o0 : ((which == 1) ? o1 : o2);
                dst[(((size_t)(b * HH + h)) * seq + s) * 64 + d] = f2bf(val);
            }
        }
    }
}

// ---------------- MFMA flash attention -------------------------------------
// Q,K,V: [B,H,S,64] bf16. O: [B*Sq, Dm] bf16 (concat heads at h*64).
// Block: 64 q-rows for one (b,h). 4 waves x 16 q-rows each.
// S^T = mfma(K_frag, Q_frag): acc rows k = 16t+g*4+r, cols q = i16 (lane-local
// softmax stats per column). P packed to LDS (4x b64/tile), PV via mfma(P, V^T).
// K_lds / Vt_lds: 128B rows with byte-XOR swizzle ((row&7)<<4) to kill the
// 16-way row-major bank conflict on ds_read_b128 (G4).
template<bool CAUSAL>
__global__ __launch_bounds__(256) void attn_mfma(
    const unsigned short* __restrict__ Q, const unsigned short* __restrict__ K,
    const unsigned short* __restrict__ V, unsigned short* __restrict__ O,
    const int* __restrict__ pidx, int Sq, int Sk, int Dm, float scale)
{
    __shared__ __align__(16) unsigned short Kls[64 * 64];   // [k][d] swizzled
    __shared__ __align__(16) unsigned short Vls[64 * 64];   // [d][k] swizzled (V^T)
    __shared__ __align__(16) unsigned short Pls[4 * 16 * 72]; // per-wave [q=16][k=72]

    const int b = blockIdx.z, h = blockIdx.y;
    const int nqt = Sq >> 6;
    const int bx = blockIdx.x;
    // heavy/light pairing for causal load balance: (0,15),(1,14),...
    const int qt = CAUSAL ? ((bx & 1) ? (nqt - 1 - (bx >> 1)) : (bx >> 1)) : bx;
    const int qbase = qt * 64;
    const int tid = threadIdx.x;
    const int w = tid >> 6, l = tid & 63;
    const int g = l >> 4, i16 = l & 15;
    const size_t hbase = (size_t)b * HH + h;

    // Q fragments (B-operand of S^T mfma): lane holds Q[q=w*16+i16][ks*32+g*8+j]
    const unsigned short* Qp = Q + (hbase * Sq + qbase + w * 16 + i16) * 64;
    const short8 qf0 = *(const short8*)(Qp + g * 8);
    const short8 qf1 = *(const short8*)(Qp + 32 + g * 8);

    int jm = 0;
    if (!CAUSAL) {
        int p = pidx[b * Sq + qbase + w * 16 + i16];
        jm = (p < Sk - 1) ? p : (Sk - 1);
    }

    f32x4 accO[4] = {{0,0,0,0},{0,0,0,0},{0,0,0,0},{0,0,0,0}};
    float mrun = -3.0e38f, lrun = 0.f;

    const int nkt = CAUSAL ? (qt + 1) : (Sk >> 6);
    const int skr = tid >> 3;            // staging K row 0..31
    const int sd0 = (tid & 7) * 8;       // staging K col

    for (int kt = 0; kt < nkt; ++kt) {
        const int kb = kt * 64;
        __syncthreads();
        // ---- stage K tile [64 k][64 d], XOR-swizzled 16B blocks ----
        const unsigned short* gK = K + (hbase * Sk + kb) * 64;
#pragma unroll
        for (int it = 0; it < 2; ++it) {
            int kr = skr + it * 32;
            uint4 kvv = *(const uint4*)(gK + kr * 64 + sd0);
            *(uint4*)((char*)Kls + kr * 128 + ((sd0 * 2) ^ ((kr & 7) << 4))) = kvv;
        }
        // ---- stage V tile transposed: Vls[d][k], swizzled ----
        const unsigned short* gV = V + (hbase * Sk + kb) * 64;
#pragma unroll
        for (int it = 0; it < 2; ++it) {
            int dd0 = w * 8 + it * 32;
            short8 vv = *(const short8*)(gV + l * 64 + dd0);
#pragma unroll
            for (int i = 0; i < 8; ++i) {
                int dr = dd0 + i;
                *(unsigned short*)((char*)Vls + dr * 128 + ((l * 2) ^ ((dr & 7) << 4)))
                    = (unsigned short)vv[i];
            }
        }
        __syncthreads();

        // ---- S^T = K @ Q^T: accS[t] rows k=kb+16t+g*4+r, cols q=i16 ----
        f32x4 accS[4] = {{0,0,0,0},{0,0,0,0},{0,0,0,0},{0,0,0,0}};
#pragma unroll
        for (int ks = 0; ks < 2; ++ks) {
            short8 qf = ks ? qf1 : qf0;
#pragma unroll
            for (int t = 0; t < 4; ++t) {
                short8 kf = *(const short8*)((char*)Kls + (16 * t + i16) * 128
                             + ((g * 16 + ks * 64) ^ ((i16 & 7) << 4)));
                accS[t] = __builtin_amdgcn_mfma_f32_16x16x32_bf16(kf, qf, accS[t], 0, 0, 0);
            }
        }

        // ---- online softmax, lane-local column q = i16 ----
        float sv[4][4];
        float mloc = -3.0e38f;
        const bool diag = CAUSAL && (kt == qt);
#pragma unroll
        for (int t = 0; t < 4; ++t) {
#pragma unroll
            for (int r = 0; r < 4; ++r) {
                float x = accS[t][r] * scale;
                if (CAUSAL) {
                    if (diag && (16 * t + g * 4 + r) > (w * 16 + i16)) x = -1.0e9f;
                } else {
                    if (kb + 16 * t + g * 4 + r > jm) x = -1.0e9f;
                }
                sv[t][r] = x;
                mloc = fmaxf(mloc, x);
            }
        }
        mloc = fmaxf(mloc, __shfl_xor(mloc, 16));
        mloc = fmaxf(mloc, __shfl_xor(mloc, 32));
        float mnew = fmaxf(mrun, mloc);
        float fac = __expf(mrun - mnew);
        float psum = 0.f;
#pragma unroll
        for (int t = 0; t < 4; ++t) {
            float p0 = __expf(sv[t][0] - mnew);
            float p1 = __expf(sv[t][1] - mnew);
            float p2 = __expf(sv[t][2] - mnew);
            float p3 = __expf(sv[t][3] - mnew);
            psum += (p0 + p1) + (p2 + p3);
            uint2 u2;
            u2.x = (unsigned int)f2bf(p0) | ((unsigned int)f2bf(p1) << 16);
            u2.y = (unsigned int)f2bf(p2) | ((unsigned int)f2bf(p3) << 16);
            *(uint2*)((char*)Pls + w * 2304 + i16 * 144 + t * 32 + g * 8) = u2;
        }
        psum += __shfl_xor(psum, 16);
        psum += __shfl_xor(psum, 32);
        lrun = lrun * fac + psum;
        mrun = mnew;
        // rescale accO rows (row q = g*4+r needs fac of column-lane g*4+r)
        float facr0 = __shfl(fac, g * 4 + 0);
        float facr1 = __shfl(fac, g * 4 + 1);
        float facr2 = __shfl(fac, g * 4 + 2);
        float facr3 = __shfl(fac, g * 4 + 3);
#pragma unroll
        for (int t = 0; t < 4; ++t) {
            accO[t][0] *= facr0; accO[t][1] *= facr1;
            accO[t][2] *= facr2; accO[t][3] *= facr3;
        }
        // ---- PV: accO[t] += P[q][k] * V[k][d] ----
#pragma unroll
        for (int ks = 0; ks < 2; ++ks) {
            short8 pf = *(const short8*)((char*)Pls + w * 2304 + i16 * 144
                          + g * 16 + ks * 64);
#pragma unroll
            for (int t = 0; t < 4; ++t) {
                short8 vf = *(const short8*)((char*)Vls + (16 * t + i16) * 128
                             + ((g * 16 + ks * 64) ^ ((i16 & 7) << 4)));
                accO[t] = __builtin_amdgcn_mfma_f32_16x16x32_bf16(pf, vf, accO[t], 0, 0, 0);
            }
        }
    }

    // ---- epilogue: normalize + store bf16 ----
    float inv = 1.0f / lrun;
    float inv0 = __shfl(inv, g * 4 + 0);
    float inv1 = __shfl(inv, g * 4 + 1);
    float inv2 = __shfl(inv, g * 4 + 2);
    float inv3 = __shfl(inv, g * 4 + 3);
    unsigned short* Orow = O + (size_t)(b * Sq + qbase + w * 16 + g * 4) * Dm
                             + h * 64 + i16;
#pragma unroll
    for (int t = 0; t < 4; ++t) {
        Orow[t * 16]                 = f2bf(accO[t][0] * inv0);
        Orow[(size_t)Dm + t * 16]    = f2bf(accO[t][1] * inv1);
        Orow[2 * (size_t)Dm + t * 16] = f2bf(accO[t][2] * inv2);
        Orow[3 * (size_t)Dm + t * 16] = f2bf(accO[t][3] * inv3);
    }
}

// ---------------------------------------------------------------------------
extern "C" void kernel_launch(void* const* d_in, const int* in_sizes, int n_in,
                              void* d_out, int out_size, void* d_ws, size_t ws_size,
                              hipStream_t stream)
{
    (void)in_sizes; (void)n_in; (void)out_size; (void)ws_size;
    const int*   byte_seq = (const int*)d_in[0];
    const float* patch    = (const float*)d_in[1];
    const int*   pbound   = (const int*)d_in[2];
    const float* byte_emb = (const float*)d_in[3];
    const float* pos_emb  = (const float*)d_in[4];
    const float* sa_in_w  = (const float*)d_in[5];
    const float* sa_in_b  = (const float*)d_in[6];
    const float* sa_out_w = (const float*)d_in[7];
    const float* sa_out_b = (const float*)d_in[8];
    const float* ca_in_w  = (const float*)d_in[9];
    const float* ca_in_b  = (const float*)d_in[10];
    const float* ca_out_w = (const float*)d_in[11];
    const float* ca_out_b = (const float*)d_in[12];
    const float* ffn_w1   = (const float*)d_in[13];
    const float* ffn_b1   = (const float*)d_in[14];
    const float* ffn_w2   = (const float*)d_in[15];
    const float* ffn_b2   = (const float*)d_in[16];
    const float* ln_g     = (const float*)d_in[17];
    const float* ln_b     = (const float*)d_in[18];
    const float* norm_g   = (const float*)d_in[19];
    const float* norm_b   = (const float*)d_in[20];
    const float* out_w    = (const float*)d_in[21];

    char* ws = (char*)d_ws;
    float*          x   = (float*)(ws + 0);                    //  8 MB fp32 residual
    unsigned short* h   = (unsigned short*)(ws + 8388608);     //  4 MB
    unsigned short* q   = (unsigned short*)(ws + 12582912);    //  4 MB
    unsigned short* k   = (unsigned short*)(ws + 16777216);    //  4 MB
    unsigned short* v   = (unsigned short*)(ws + 20971520);    //  4 MB
    unsigned short* aO  = (unsigned short*)(ws + 25165824);    //  4 MB
    unsigned short* u   = (unsigned short*)(ws + 12582912);    // 16 MB, aliases q/k/v/aO (dead by FFN)
    unsigned short* kca = (unsigned short*)(ws + 29360128);    // 512 KB
    unsigned short* vca = (unsigned short*)(ws + 29884416);    // 512 KB
    unsigned short* pp  = (unsigned short*)(ws + 30408704);    // 512 KB patch bf16
    int*            pidx = (int*)(ws + 30932992);              //   8 KB

    embed_kernel<<<(NN * DDIM + 255) / 256, 256, 0, stream>>>(byte_seq, byte_emb, pos_emb, x);
    cvt_bf16_kernel<<<(BD * PP * DDIM + 255) / 256, 256, 0, stream>>>(patch, pp, BD * PP * DDIM);
    pidx_kernel<<<1, 64, 0, stream>>>(pbound, pidx);

    for (int l = 0; l < LL; ++l) {
        const float* lg = ln_g + (size_t)(l * 3) * DDIM;
        const float* lb = ln_b + (size_t)(l * 3) * DDIM;
        // ---- self-attention block ----
        ln_kernel<<<NN, 256, 0, stream>>>(x, lg, lb, h);
        gemm_bt<3><<<dim3(3 * DDIM / 64, NN / 64), 256, 0, stream>>>(
            h, sa_in_w + (size_t)l * 3 * DDIM * DDIM, sa_in_b + (size_t)l * 3 * DDIM,
            nullptr, q, k, v, NN, 3 * DDIM, DDIM, SD);
        attn_mfma<true><<<dim3(SD / 64, HH, BD), 256, 0, stream>>>(
            q, k, v, aO, nullptr, SD, SD, DDIM, 0.125f);
        gemm_bt<1><<<dim3(DDIM / 64, NN / 64), 256, 0, stream>>>(
            aO, sa_out_w + (size_t)l * DDIM * DDIM, sa_out_b + (size_t)l * DDIM,
            x, nullptr, nullptr, nullptr, NN, DDIM, DDIM, 0);
        // ---- cross-attention block ----
        ln_kernel<<<NN, 256, 0, stream>>>(x, lg + DDIM, lb + DDIM, h);
        gemm_bt<3><<<dim3(DDIM / 64, NN / 64), 256, 0, stream>>>(
            h, ca_in_w + (size_t)l * 3 * DDIM * DDIM, ca_in_b + (size_t)l * 3 * DDIM,
            nullptr, q, nullptr, nullptr, NN, DDIM, DDIM, SD);
        gemm_bt<3><<<dim3(2 * DDIM / 64, (BD * PP) / 64), 256, 0, stream>>>(
            pp, ca_in_w + (size_t)l * 3 * DDIM * DDIM + (size_t)DDIM * DDIM,
            ca_in_b + (size_t)l * 3 * DDIM + DDIM,
            nullptr, kca, vca, nullptr, BD * PP, 2 * DDIM, DDIM, PP);
        attn_mfma<false><<<dim3(SD / 64, HH, BD), 256, 0, stream>>>(
            q, kca, vca, aO, pidx, SD, PP, DDIM, 0.125f);
        gemm_bt<1><<<dim3(DDIM / 64, NN / 64), 256, 0, stream>>>(
            aO, ca_out_w + (size_t)l * DDIM * DDIM, ca_out_b + (size_t)l * DDIM,
            x, nullptr, nullptr, nullptr, NN, DDIM, DDIM, 0);
        // ---- FFN block ----
        ln_kernel<<<NN, 256, 0, stream>>>(x, lg + 2 * DDIM, lb + 2 * DDIM, h);
        gemm_bt<2><<<dim3(4 * DDIM / 64, NN / 64), 256, 0, stream>>>(
            h, ffn_w1 + (size_t)l * 4 * DDIM * DDIM, ffn_b1 + (size_t)l * 4 * DDIM,
            nullptr, u, nullptr, nullptr, NN, 4 * DDIM, DDIM, 0);
        gemm_bt<1><<<dim3(DDIM / 64, NN / 64), 256, 0, stream>>>(
            u, ffn_w2 + (size_t)l * DDIM * 4 * DDIM, ffn_b2 + (size_t)l * DDIM,
            x, nullptr, nullptr, nullptr, NN, DDIM, 4 * DDIM, 0);
    }
    ln_kernel<<<NN, 256, 0, stream>>>(x, norm_g, norm_b, h);
    gemm_bt<0><<<dim3(VV / 64, NN / 64), 256, 0, stream>>>(
        h, out_w, nullptr, (float*)d_out, nullptr, nullptr, nullptr,
        NN, VV, DDIM, 0);
}

// Round 2
// 3198.094 us; speedup vs baseline: 3.6743x; 1.2332x over previous
//
#include <hip/hip_runtime.h>
#include <math.h>
#include <stdint.h>

#define BD 2
#define SD 1024
#define DDIM 1024
#define HH 16
#define LL 9
#define WW 1024
#define PP 128
#define VV 256
#define NN (BD*SD)

typedef __attribute__((ext_vector_type(8))) short short8;
typedef __attribute__((ext_vector_type(4))) float f32x4;
typedef unsigned int u32;

__device__ __forceinline__ float bf2f(unsigned int u) {
    return __uint_as_float((u & 0xffffu) << 16);
}
__device__ __forceinline__ unsigned short f2bf(float f) {
    unsigned int u = __float_as_uint(f);
    unsigned int r = (u + 0x7fffu + ((u >> 16) & 1u)) >> 16;
    return (unsigned short)r;
}

// async global->LDS, 16B per lane. LDS dest must be wave-uniform base + lane*16.
__device__ __forceinline__ void gload_lds16(const unsigned short* g, void* l) {
    __builtin_amdgcn_global_load_lds(
        (const __attribute__((address_space(1))) u32*)(const void*)g,
        (__attribute__((address_space(3))) u32*)(u32)(uintptr_t)l,
        16, 0, 0);
}

__device__ __forceinline__ float block_reduce_sum(float v, float* red) {
#pragma unroll
    for (int off = 32; off > 0; off >>= 1) v += __shfl_down(v, off);
    __syncthreads();
    if ((threadIdx.x & 63) == 0) red[threadIdx.x >> 6] = v;
    __syncthreads();
    return red[0] + red[1] + red[2] + red[3];
}

// ---------------- embed: x = byte_emb[tok] + pos_emb[s] (fp32) ----------------
__global__ __launch_bounds__(256) void embed_kernel(
    const int* __restrict__ seq, const float* __restrict__ bemb,
    const float* __restrict__ pemb, float* __restrict__ x)
{
    int i = blockIdx.x * 256 + threadIdx.x;
    if (i >= NN * DDIM) return;
    int n = i >> 10, d = i & 1023;
    int s = n & (SD - 1);
    int tok = seq[n];
    x[i] = bemb[tok * DDIM + d] + pemb[s * DDIM + d];
}

// ---------------- fp32 -> bf16 (generic) ----------------
__global__ __launch_bounds__(256) void cvt_bf16_kernel(
    const float* __restrict__ in, unsigned short* __restrict__ out, int n)
{
    int i = blockIdx.x * 256 + threadIdx.x;
    if (i < n) out[i] = f2bf(in[i]);
}

// ---------------- per-layer fused weight fp32->bf16 ------------------------
// groups of 4 elems. layout (elems): sa_in@0(3M) sa_out@3M(1M) ca_in@4M(3M)
// ca_out@7M(1M) ffn1@8M(4M) ffn2@12M(4M); total 16M elems.
__global__ __launch_bounds__(256) void cvt_wts_kernel(
    const float* __restrict__ s0, const float* __restrict__ s1,
    const float* __restrict__ s2, const float* __restrict__ s3,
    const float* __restrict__ s4, const float* __restrict__ s5,
    unsigned short* __restrict__ out)
{
    int i = blockIdx.x * 256 + threadIdx.x;
    const float* src; int off, obase;
    if (i < 786432)       { src = s0; off = i;           obase = 0; }
    else if (i < 1048576) { src = s1; off = i - 786432;  obase = 786432; }
    else if (i < 1835008) { src = s2; off = i - 1048576; obase = 1048576; }
    else if (i < 2097152) { src = s3; off = i - 1835008; obase = 1835008; }
    else if (i < 3145728) { src = s4; off = i - 2097152; obase = 2097152; }
    else                  { src = s5; off = i - 3145728; obase = 3145728; }
    float4 v4 = ((const float4*)src)[off];
    ushort4 o;
    o.x = f2bf(v4.x); o.y = f2bf(v4.y); o.z = f2bf(v4.z); o.w = f2bf(v4.w);
    ((ushort4*)out)[obase + off] = o;
}

// ---------------- pidx = inclusive cumsum of patch_boundaries ----------------
__global__ void pidx_kernel(const int* __restrict__ pb, int* __restrict__ pidx)
{
    int b = threadIdx.x;
    if (b < BD) {
        int c = 0;
        for (int s = 0; s < SD; ++s) { c += pb[b * SD + s]; pidx[b * SD + s] = c; }
    }
}

// ---------------- LayerNorm: fp32 in -> bf16 out ----------------
__global__ __launch_bounds__(256) void ln_kernel(
    const float* __restrict__ x, const float* __restrict__ gg,
    const float* __restrict__ bb, unsigned short* __restrict__ out)
{
    __shared__ float red[4];
    const int row = blockIdx.x, tid = threadIdx.x;
    const float* xr = x + (size_t)row * DDIM;
    float v[4]; float s = 0.f, s2 = 0.f;
#pragma unroll
    for (int i = 0; i < 4; ++i) {
        float t = xr[tid + i * 256]; v[i] = t; s += t; s2 += t * t;
    }
    s = block_reduce_sum(s, red);
    __syncthreads();
    s2 = block_reduce_sum(s2, red);
    float mean = s * (1.f / DDIM);
    float var = s2 * (1.f / DDIM) - mean * mean;
    float rs = rsqrtf(var + 1e-5f);
    unsigned short* orow = out + (size_t)row * DDIM;
#pragma unroll
    for (int i = 0; i < 4; ++i) {
        int c = tid + i * 256;
        orow[c] = f2bf((v[i] - mean) * rs * gg[c] + bb[c]);
    }
}

// ---------------- GEMM (m97 structure): C[M,N] = A[M,K]bf16 @ B[N,K]bf16^T --
// 256 threads = 4 waves in 2x2 grid; wave tile (BM/2)x(BN/2); BK=32.
// global_load_lds(16B) staging, linear LDS [rows][32] (64B rows).
// MODE 0: store fp32; 1: resid +=; 2: bf16 gelu -> o0; 3: qkv scatter.
template<int BM, int BN, int MODE>
__global__ __launch_bounds__(256) void gemm_mfma(
    const unsigned short* __restrict__ A, const unsigned short* __restrict__ B,
    const float* __restrict__ bias, float* __restrict__ resid,
    unsigned short* __restrict__ o0, unsigned short* __restrict__ o1,
    unsigned short* __restrict__ o2, int M, int N, int K, int seq)
{
    constexpr int WM = BM / 2, WN = BN / 2;
    constexpr int FM = WM / 16, FN = WN / 16;
    __shared__ __align__(16) unsigned short As[BM * 32];
    __shared__ __align__(16) unsigned short Bs[BN * 32];
    const int tid = threadIdx.x;
    const int m0 = blockIdx.y * BM, n0 = blockIdx.x * BN;
    const int w = tid >> 6, l = tid & 63, g = l >> 4, i16 = l & 15;
    const int wr = w >> 1, wc = w & 1;
    f32x4 acc[FM][FN] = {};

    // staging: call c covers rows c*64 + tid/4, k = (tid&3)*8; LDS byte = c*4096 + tid*16
    const unsigned short* gA = A + (size_t)(m0 + (tid >> 2)) * K + (tid & 3) * 8;
    const unsigned short* gB = B + (size_t)(n0 + (tid >> 2)) * K + (tid & 3) * 8;
    char* AsB = (char*)As;
    char* BsB = (char*)Bs;

    for (int k0 = 0; k0 < K; k0 += 32) {
        __syncthreads();
        gload_lds16(gA, AsB + tid * 16);
        if constexpr (BM == 128) gload_lds16(gA + (size_t)64 * K, AsB + 4096 + tid * 16);
        gload_lds16(gB, BsB + tid * 16);
        if constexpr (BN == 128) gload_lds16(gB + (size_t)64 * K, BsB + 4096 + tid * 16);
        gA += 32; gB += 32;
        __syncthreads();   // compiler drains vmcnt before s_barrier

        short8 af[FM], bf[FN];
#pragma unroll
        for (int mi = 0; mi < FM; ++mi)
            af[mi] = *(const short8*)(AsB + (wr * WM + mi * 16 + i16) * 64 + g * 16);
#pragma unroll
        for (int ni = 0; ni < FN; ++ni)
            bf[ni] = *(const short8*)(BsB + (wc * WN + ni * 16 + i16) * 64 + g * 16);
#pragma unroll
        for (int mi = 0; mi < FM; ++mi)
#pragma unroll
            for (int ni = 0; ni < FN; ++ni)
                acc[mi][ni] = __builtin_amdgcn_mfma_f32_16x16x32_bf16(
                    af[mi], bf[ni], acc[mi][ni], 0, 0, 0);
    }

#pragma unroll
    for (int mi = 0; mi < FM; ++mi) {
#pragma unroll
        for (int ni = 0; ni < FN; ++ni) {
            const int gcol = n0 + wc * WN + ni * 16 + i16;
            const float bv = bias ? bias[gcol] : 0.f;
#pragma unroll
            for (int r = 0; r < 4; ++r) {
                const int grow = m0 + wr * WM + mi * 16 + g * 4 + r;
                float val = acc[mi][ni][r] + bv;
                if constexpr (MODE == 0) {
                    resid[(size_t)grow * N + gcol] = val;
                } else if constexpr (MODE == 1) {
                    resid[(size_t)grow * N + gcol] += val;
                } else if constexpr (MODE == 2) {
                    float gl = 0.5f * val * (1.0f + erff(val * 0.70710678118f));
                    o0[(size_t)grow * N + gcol] = f2bf(gl);
                } else {
                    int which = gcol >> 10;
                    int cD = gcol & 1023;
                    int h = cD >> 6, d = cD & 63;
                    int b = grow / seq, s = grow % seq;
                    unsigned short* dst = (which == 0) ? o0 : ((which == 1) ? o1 : o2);
                    dst[(((size_t)(b * HH + h)) * seq + s) * 64 + d] = f2bf(val);
                }
            }
        }
    }
}

// ---------------- MFMA flash attention (unchanged from R1) -----------------
template<bool CAUSAL>
__global__ __launch_bounds__(256) void attn_mfma(
    const unsigned short* __restrict__ Q, const unsigned short* __restrict__ K,
    const unsigned short* __restrict__ V, unsigned short* __restrict__ O,
    const int* __restrict__ pidx, int Sq, int Sk, int Dm, float scale)
{
    __shared__ __align__(16) unsigned short Kls[64 * 64];
    __shared__ __align__(16) unsigned short Vls[64 * 64];
    __shared__ __align__(16) unsigned short Pls[4 * 16 * 72];

    const int b = blockIdx.z, h = blockIdx.y;
    const int nqt = Sq >> 6;
    const int bx = blockIdx.x;
    const int qt = CAUSAL ? ((bx & 1) ? (nqt - 1 - (bx >> 1)) : (bx >> 1)) : bx;
    const int qbase = qt * 64;
    const int tid = threadIdx.x;
    const int w = tid >> 6, l = tid & 63;
    const int g = l >> 4, i16 = l & 15;
    const size_t hbase = (size_t)b * HH + h;

    const unsigned short* Qp = Q + (hbase * Sq + qbase + w * 16 + i16) * 64;
    const short8 qf0 = *(const short8*)(Qp + g * 8);
    const short8 qf1 = *(const short8*)(Qp + 32 + g * 8);

    int jm = 0;
    if (!CAUSAL) {
        int p = pidx[b * Sq + qbase + w * 16 + i16];
        jm = (p < Sk - 1) ? p : (Sk - 1);
    }

    f32x4 accO[4] = {{0,0,0,0},{0,0,0,0},{0,0,0,0},{0,0,0,0}};
    float mrun = -3.0e38f, lrun = 0.f;

    const int nkt = CAUSAL ? (qt + 1) : (Sk >> 6);
    const int skr = tid >> 3;
    const int sd0 = (tid & 7) * 8;

    for (int kt = 0; kt < nkt; ++kt) {
        const int kb = kt * 64;
        __syncthreads();
        const unsigned short* gK = K + (hbase * Sk + kb) * 64;
#pragma unroll
        for (int it = 0; it < 2; ++it) {
            int kr = skr + it * 32;
            uint4 kvv = *(const uint4*)(gK + kr * 64 + sd0);
            *(uint4*)((char*)Kls + kr * 128 + ((sd0 * 2) ^ ((kr & 7) << 4))) = kvv;
        }
        const unsigned short* gV = V + (hbase * Sk + kb) * 64;
#pragma unroll
        for (int it = 0; it < 2; ++it) {
            int dd0 = w * 8 + it * 32;
            short8 vv = *(const short8*)(gV + l * 64 + dd0);
#pragma unroll
            for (int i = 0; i < 8; ++i) {
                int dr = dd0 + i;
                *(unsigned short*)((char*)Vls + dr * 128 + ((l * 2) ^ ((dr & 7) << 4)))
                    = (unsigned short)vv[i];
            }
        }
        __syncthreads();

        f32x4 accS[4] = {{0,0,0,0},{0,0,0,0},{0,0,0,0},{0,0,0,0}};
#pragma unroll
        for (int ks = 0; ks < 2; ++ks) {
            short8 qf = ks ? qf1 : qf0;
#pragma unroll
            for (int t = 0; t < 4; ++t) {
                short8 kf = *(const short8*)((char*)Kls + (16 * t + i16) * 128
                             + ((g * 16 + ks * 64) ^ ((i16 & 7) << 4)));
                accS[t] = __builtin_amdgcn_mfma_f32_16x16x32_bf16(kf, qf, accS[t], 0, 0, 0);
            }
        }

        float sv[4][4];
        float mloc = -3.0e38f;
        const bool diag = CAUSAL && (kt == qt);
#pragma unroll
        for (int t = 0; t < 4; ++t) {
#pragma unroll
            for (int r = 0; r < 4; ++r) {
                float x = accS[t][r] * scale;
                if (CAUSAL) {
                    if (diag && (16 * t + g * 4 + r) > (w * 16 + i16)) x = -1.0e9f;
                } else {
                    if (kb + 16 * t + g * 4 + r > jm) x = -1.0e9f;
                }
                sv[t][r] = x;
                mloc = fmaxf(mloc, x);
            }
        }
        mloc = fmaxf(mloc, __shfl_xor(mloc, 16));
        mloc = fmaxf(mloc, __shfl_xor(mloc, 32));
        float mnew = fmaxf(mrun, mloc);
        float fac = __expf(mrun - mnew);
        float psum = 0.f;
#pragma unroll
        for (int t = 0; t < 4; ++t) {
            float p0 = __expf(sv[t][0] - mnew);
            float p1 = __expf(sv[t][1] - mnew);
            float p2 = __expf(sv[t][2] - mnew);
            float p3 = __expf(sv[t][3] - mnew);
            psum += (p0 + p1) + (p2 + p3);
            uint2 u2;
            u2.x = (unsigned int)f2bf(p0) | ((unsigned int)f2bf(p1) << 16);
            u2.y = (unsigned int)f2bf(p2) | ((unsigned int)f2bf(p3) << 16);
            *(uint2*)((char*)Pls + w * 2304 + i16 * 144 + t * 32 + g * 8) = u2;
        }
        psum += __shfl_xor(psum, 16);
        psum += __shfl_xor(psum, 32);
        lrun = lrun * fac + psum;
        mrun = mnew;
        float facr0 = __shfl(fac, g * 4 + 0);
        float facr1 = __shfl(fac, g * 4 + 1);
        float facr2 = __shfl(fac, g * 4 + 2);
        float facr3 = __shfl(fac, g * 4 + 3);
#pragma unroll
        for (int t = 0; t < 4; ++t) {
            accO[t][0] *= facr0; accO[t][1] *= facr1;
            accO[t][2] *= facr2; accO[t][3] *= facr3;
        }
#pragma unroll
        for (int ks = 0; ks < 2; ++ks) {
            short8 pf = *(const short8*)((char*)Pls + w * 2304 + i16 * 144
                          + g * 16 + ks * 64);
#pragma unroll
            for (int t = 0; t < 4; ++t) {
                short8 vf = *(const short8*)((char*)Vls + (16 * t + i16) * 128
                             + ((g * 16 + ks * 64) ^ ((i16 & 7) << 4)));
                accO[t] = __builtin_amdgcn_mfma_f32_16x16x32_bf16(pf, vf, accO[t], 0, 0, 0);
            }
        }
    }

    float inv = 1.0f / lrun;
    float inv0 = __shfl(inv, g * 4 + 0);
    float inv1 = __shfl(inv, g * 4 + 1);
    float inv2 = __shfl(inv, g * 4 + 2);
    float inv3 = __shfl(inv, g * 4 + 3);
    unsigned short* Orow = O + (size_t)(b * Sq + qbase + w * 16 + g * 4) * Dm
                             + h * 64 + i16;
#pragma unroll
    for (int t = 0; t < 4; ++t) {
        Orow[t * 16]                 = f2bf(accO[t][0] * inv0);
        Orow[(size_t)Dm + t * 16]    = f2bf(accO[t][1] * inv1);
        Orow[2 * (size_t)Dm + t * 16] = f2bf(accO[t][2] * inv2);
        Orow[3 * (size_t)Dm + t * 16] = f2bf(accO[t][3] * inv3);
    }
}

// ---------------------------------------------------------------------------
extern "C" void kernel_launch(void* const* d_in, const int* in_sizes, int n_in,
                              void* d_out, int out_size, void* d_ws, size_t ws_size,
                              hipStream_t stream)
{
    (void)in_sizes; (void)n_in; (void)out_size; (void)ws_size;
    const int*   byte_seq = (const int*)d_in[0];
    const float* patch    = (const float*)d_in[1];
    const int*   pbound   = (const int*)d_in[2];
    const float* byte_emb = (const float*)d_in[3];
    const float* pos_emb  = (const float*)d_in[4];
    const float* sa_in_w  = (const float*)d_in[5];
    const float* sa_in_b  = (const float*)d_in[6];
    const float* sa_out_w = (const float*)d_in[7];
    const float* sa_out_b = (const float*)d_in[8];
    const float* ca_in_w  = (const float*)d_in[9];
    const float* ca_in_b  = (const float*)d_in[10];
    const float* ca_out_w = (const float*)d_in[11];
    const float* ca_out_b = (const float*)d_in[12];
    const float* ffn_w1   = (const float*)d_in[13];
    const float* ffn_b1   = (const float*)d_in[14];
    const float* ffn_w2   = (const float*)d_in[15];
    const float* ffn_b2   = (const float*)d_in[16];
    const float* ln_g     = (const float*)d_in[17];
    const float* ln_b     = (const float*)d_in[18];
    const float* norm_g   = (const float*)d_in[19];
    const float* norm_b   = (const float*)d_in[20];
    const float* out_w    = (const float*)d_in[21];

    char* ws = (char*)d_ws;
    float*          x   = (float*)(ws + 0);                    //  8 MB fp32 residual
    unsigned short* h   = (unsigned short*)(ws + 8388608);     //  4 MB
    unsigned short* q   = (unsigned short*)(ws + 12582912);    //  4 MB
    unsigned short* k   = (unsigned short*)(ws + 16777216);    //  4 MB
    unsigned short* v   = (unsigned short*)(ws + 20971520);    //  4 MB
    unsigned short* aO  = (unsigned short*)(ws + 25165824);    //  4 MB
    unsigned short* u   = (unsigned short*)(ws + 12582912);    // 16 MB, aliases q/k/v/aO
    unsigned short* kca = (unsigned short*)(ws + 29360128);    // 512 KB
    unsigned short* vca = (unsigned short*)(ws + 29884416);    // 512 KB
    unsigned short* pp  = (unsigned short*)(ws + 30408704);    // 512 KB patch bf16
    int*            pidx = (int*)(ws + 30932992);              //   8 KB
    unsigned short* wb  = (unsigned short*)(ws + 31457280);    // 32 MB layer weights bf16
    unsigned short* wout = (unsigned short*)(ws + 65011712);   // 512 KB out_w bf16

    embed_kernel<<<(NN * DDIM + 255) / 256, 256, 0, stream>>>(byte_seq, byte_emb, pos_emb, x);
    cvt_bf16_kernel<<<(BD * PP * DDIM + 255) / 256, 256, 0, stream>>>(patch, pp, BD * PP * DDIM);
    cvt_bf16_kernel<<<(VV * DDIM + 255) / 256, 256, 0, stream>>>(out_w, wout, VV * DDIM);
    pidx_kernel<<<1, 64, 0, stream>>>(pbound, pidx);

    // bf16 weight slots (element offsets in wb)
    unsigned short* wb_sa_in  = wb + 0;
    unsigned short* wb_sa_out = wb + 3145728;
    unsigned short* wb_ca_in  = wb + 4194304;
    unsigned short* wb_ca_kv  = wb + 4194304 + DDIM * DDIM;   // k/v rows of ca_in
    unsigned short* wb_ca_out = wb + 7340032;
    unsigned short* wb_ffn1   = wb + 8388608;
    unsigned short* wb_ffn2   = wb + 12582912;

    for (int l = 0; l < LL; ++l) {
        const float* lg = ln_g + (size_t)(l * 3) * DDIM;
        const float* lb = ln_b + (size_t)(l * 3) * DDIM;

        cvt_wts_kernel<<<16384, 256, 0, stream>>>(
            sa_in_w + (size_t)l * 3 * DDIM * DDIM, sa_out_w + (size_t)l * DDIM * DDIM,
            ca_in_w + (size_t)l * 3 * DDIM * DDIM, ca_out_w + (size_t)l * DDIM * DDIM,
            ffn_w1 + (size_t)l * 4 * DDIM * DDIM, ffn_w2 + (size_t)l * 4 * DDIM * DDIM,
            wb);

        // ---- self-attention block ----
        ln_kernel<<<NN, 256, 0, stream>>>(x, lg, lb, h);
        gemm_mfma<128, 128, 3><<<dim3(3 * DDIM / 128, NN / 128), 256, 0, stream>>>(
            h, wb_sa_in, sa_in_b + (size_t)l * 3 * DDIM,
            nullptr, q, k, v, NN, 3 * DDIM, DDIM, SD);
        attn_mfma<true><<<dim3(SD / 64, HH, BD), 256, 0, stream>>>(
            q, k, v, aO, nullptr, SD, SD, DDIM, 0.125f);
        gemm_mfma<64, 128, 1><<<dim3(DDIM / 128, NN / 64), 256, 0, stream>>>(
            aO, wb_sa_out, sa_out_b + (size_t)l * DDIM,
            x, nullptr, nullptr, nullptr, NN, DDIM, DDIM, 0);

        // ---- cross-attention block ----
        ln_kernel<<<NN, 256, 0, stream>>>(x, lg + DDIM, lb + DDIM, h);
        gemm_mfma<64, 128, 3><<<dim3(DDIM / 128, NN / 64), 256, 0, stream>>>(
            h, wb_ca_in, ca_in_b + (size_t)l * 3 * DDIM,
            nullptr, q, nullptr, nullptr, NN, DDIM, DDIM, SD);
        gemm_mfma<64, 128, 3><<<dim3(2 * DDIM / 128, (BD * PP) / 64), 256, 0, stream>>>(
            pp, wb_ca_kv, ca_in_b + (size_t)l * 3 * DDIM + DDIM,
            nullptr, kca, vca, nullptr, BD * PP, 2 * DDIM, DDIM, PP);
        attn_mfma<false><<<dim3(SD / 64, HH, BD), 256, 0, stream>>>(
            q, kca, vca, aO, pidx, SD, PP, DDIM, 0.125f);
        gemm_mfma<64, 128, 1><<<dim3(DDIM / 128, NN / 64), 256, 0, stream>>>(
            aO, wb_ca_out, ca_out_b + (size_t)l * DDIM,
            x, nullptr, nullptr, nullptr, NN, DDIM, DDIM, 0);

        // ---- FFN block ----
        ln_kernel<<<NN, 256, 0, stream>>>(x, lg + 2 * DDIM, lb + 2 * DDIM, h);
        gemm_mfma<128, 128, 2><<<dim3(4 * DDIM / 128, NN / 128), 256, 0, stream>>>(
            h, wb_ffn1, ffn_b1 + (size_t)l * 4 * DDIM,
            nullptr, u, nullptr, nullptr, NN, 4 * DDIM, DDIM, 0);
        gemm_mfma<64, 128, 1><<<dim3(DDIM / 128, NN / 64), 256, 0, stream>>>(
            u, wb_ffn2, ffn_b2 + (size_t)l * DDIM,
            x, nullptr, nullptr, nullptr, NN, DDIM, 4 * DDIM, 0);
    }
    ln_kernel<<<NN, 256, 0, stream>>>(x, norm_g, norm_b, h);
    gemm_mfma<64, 64, 0><<<dim3(VV / 64, NN / 64), 256, 0, stream>>>(
        h, wout, nullptr, (float*)d_out, nullptr, nullptr, nullptr,
        NN, VV, DDIM, 0);
}

// Round 3
// 2931.111 us; speedup vs baseline: 4.0090x; 1.0911x over previous
//
#include <hip/hip_runtime.h>
#include <math.h>
#include <stdint.h>

#define BD 2
#define SD 1024
#define DDIM 1024
#define HH 16
#define LL 9
#define WW 1024
#define PP 128
#define VV 256
#define NN (BD*SD)

typedef __attribute__((ext_vector_type(8))) short short8;
typedef __attribute__((ext_vector_type(4))) float f32x4;
typedef unsigned int u32;

__device__ __forceinline__ float bf2f(unsigned int u) {
    return __uint_as_float((u & 0xffffu) << 16);
}
__device__ __forceinline__ unsigned short f2bf(float f) {
    unsigned int u = __float_as_uint(f);
    unsigned int r = (u + 0x7fffu + ((u >> 16) & 1u)) >> 16;
    return (unsigned short)r;
}

// async global->LDS, 16B per lane. LDS dest must be wave-uniform base + lane*16.
__device__ __forceinline__ void gload_lds16(const unsigned short* g, void* l) {
    __builtin_amdgcn_global_load_lds(
        (const __attribute__((address_space(1))) u32*)(const void*)g,
        (__attribute__((address_space(3))) u32*)(u32)(uintptr_t)l,
        16, 0, 0);
}

__device__ __forceinline__ float block_reduce_sum(float v, float* red) {
#pragma unroll
    for (int off = 32; off > 0; off >>= 1) v += __shfl_down(v, off);
    __syncthreads();
    if ((threadIdx.x & 63) == 0) red[threadIdx.x >> 6] = v;
    __syncthreads();
    return red[0] + red[1] + red[2] + red[3];
}

// ---------------- embed: x = byte_emb[tok] + pos_emb[s] (fp32) ----------------
__global__ __launch_bounds__(256) void embed_kernel(
    const int* __restrict__ seq, const float* __restrict__ bemb,
    const float* __restrict__ pemb, float* __restrict__ x)
{
    int i = blockIdx.x * 256 + threadIdx.x;
    if (i >= NN * DDIM) return;
    int n = i >> 10, d = i & 1023;
    int s = n & (SD - 1);
    int tok = seq[n];
    x[i] = bemb[tok * DDIM + d] + pemb[s * DDIM + d];
}

// ---------------- fp32 -> bf16 (generic) ----------------
__global__ __launch_bounds__(256) void cvt_bf16_kernel(
    const float* __restrict__ in, unsigned short* __restrict__ out, int n)
{
    int i = blockIdx.x * 256 + threadIdx.x;
    if (i < n) out[i] = f2bf(in[i]);
}

// ---------------- per-layer fused weight fp32->bf16 ------------------------
__global__ __launch_bounds__(256) void cvt_wts_kernel(
    const float* __restrict__ s0, const float* __restrict__ s1,
    const float* __restrict__ s2, const float* __restrict__ s3,
    const float* __restrict__ s4, const float* __restrict__ s5,
    unsigned short* __restrict__ out)
{
    int i = blockIdx.x * 256 + threadIdx.x;
    const float* src; int off, obase;
    if (i < 786432)       { src = s0; off = i;           obase = 0; }
    else if (i < 1048576) { src = s1; off = i - 786432;  obase = 786432; }
    else if (i < 1835008) { src = s2; off = i - 1048576; obase = 1048576; }
    else if (i < 2097152) { src = s3; off = i - 1835008; obase = 1835008; }
    else if (i < 3145728) { src = s4; off = i - 2097152; obase = 2097152; }
    else                  { src = s5; off = i - 3145728; obase = 3145728; }
    float4 v4 = ((const float4*)src)[off];
    ushort4 o;
    o.x = f2bf(v4.x); o.y = f2bf(v4.y); o.z = f2bf(v4.z); o.w = f2bf(v4.w);
    ((ushort4*)out)[obase + off] = o;
}

// ---------------- pidx = inclusive cumsum of patch_boundaries ----------------
__global__ void pidx_kernel(const int* __restrict__ pb, int* __restrict__ pidx)
{
    int b = threadIdx.x;
    if (b < BD) {
        int c = 0;
        for (int s = 0; s < SD; ++s) { c += pb[b * SD + s]; pidx[b * SD + s] = c; }
    }
}

// ---------------- LayerNorm: fp32 in -> bf16 out ----------------
__global__ __launch_bounds__(256) void ln_kernel(
    const float* __restrict__ x, const float* __restrict__ gg,
    const float* __restrict__ bb, unsigned short* __restrict__ out)
{
    __shared__ float red[4];
    const int row = blockIdx.x, tid = threadIdx.x;
    const float* xr = x + (size_t)row * DDIM;
    float v[4]; float s = 0.f, s2 = 0.f;
#pragma unroll
    for (int i = 0; i < 4; ++i) {
        float t = xr[tid + i * 256]; v[i] = t; s += t; s2 += t * t;
    }
    s = block_reduce_sum(s, red);
    __syncthreads();
    s2 = block_reduce_sum(s2, red);
    float mean = s * (1.f / DDIM);
    float var = s2 * (1.f / DDIM) - mean * mean;
    float rs = rsqrtf(var + 1e-5f);
    unsigned short* orow = out + (size_t)row * DDIM;
#pragma unroll
    for (int i = 0; i < 4; ++i) {
        int c = tid + i * 256;
        orow[c] = f2bf((v[i] - mean) * rs * gg[c] + bb[c]);
    }
}

// ---------------- GEMM (m97 structure): C[M,N] = A[M,K]bf16 @ B[N,K]bf16^T --
// 256 threads = 4 waves in 2x2 grid; wave tile (BM/2)x(BN/2); BK=32.
// global_load_lds(16B) staging, linear LDS [rows][32] (64B rows).
// MODE 0: store fp32; 1: resid += (atomic if SPLITK>1); 2: bf16 gelu -> o0;
// 3: qkv scatter. SPLITK: blockIdx.z splits K; bias applied by kz==0 only.
template<int BM, int BN, int MODE, int SPLITK>
__global__ __launch_bounds__(256) void gemm_mfma(
    const unsigned short* __restrict__ A, const unsigned short* __restrict__ B,
    const float* __restrict__ bias, float* __restrict__ resid,
    unsigned short* __restrict__ o0, unsigned short* __restrict__ o1,
    unsigned short* __restrict__ o2, int M, int N, int K, int seq)
{
    constexpr int WM = BM / 2, WN = BN / 2;
    constexpr int FM = WM / 16, FN = WN / 16;
    __shared__ __align__(16) unsigned short As[BM * 32];
    __shared__ __align__(16) unsigned short Bs[BN * 32];
    const int tid = threadIdx.x;
    const int m0 = blockIdx.y * BM, n0 = blockIdx.x * BN;
    const int kz = (SPLITK > 1) ? blockIdx.z : 0;
    const int Kc = K / SPLITK;
    const int kbeg = kz * Kc;
    const int w = tid >> 6, l = tid & 63, g = l >> 4, i16 = l & 15;
    const int wr = w >> 1, wc = w & 1;
    f32x4 acc[FM][FN] = {};

    const unsigned short* gA = A + (size_t)(m0 + (tid >> 2)) * K + kbeg + (tid & 3) * 8;
    const unsigned short* gB = B + (size_t)(n0 + (tid >> 2)) * K + kbeg + (tid & 3) * 8;
    char* AsB = (char*)As;
    char* BsB = (char*)Bs;

    for (int k0 = 0; k0 < Kc; k0 += 32) {
        __syncthreads();
        gload_lds16(gA, AsB + tid * 16);
        if constexpr (BM == 128) gload_lds16(gA + (size_t)64 * K, AsB + 4096 + tid * 16);
        gload_lds16(gB, BsB + tid * 16);
        if constexpr (BN == 128) gload_lds16(gB + (size_t)64 * K, BsB + 4096 + tid * 16);
        gA += 32; gB += 32;
        __syncthreads();   // compiler drains vmcnt before s_barrier

        short8 af[FM], bf[FN];
#pragma unroll
        for (int mi = 0; mi < FM; ++mi)
            af[mi] = *(const short8*)(AsB + (wr * WM + mi * 16 + i16) * 64 + g * 16);
#pragma unroll
        for (int ni = 0; ni < FN; ++ni)
            bf[ni] = *(const short8*)(BsB + (wc * WN + ni * 16 + i16) * 64 + g * 16);
#pragma unroll
        for (int mi = 0; mi < FM; ++mi)
#pragma unroll
            for (int ni = 0; ni < FN; ++ni)
                acc[mi][ni] = __builtin_amdgcn_mfma_f32_16x16x32_bf16(
                    af[mi], bf[ni], acc[mi][ni], 0, 0, 0);
    }

#pragma unroll
    for (int mi = 0; mi < FM; ++mi) {
#pragma unroll
        for (int ni = 0; ni < FN; ++ni) {
            const int gcol = n0 + wc * WN + ni * 16 + i16;
            const float bv = (bias && kz == 0) ? bias[gcol] : 0.f;
#pragma unroll
            for (int r = 0; r < 4; ++r) {
                const int grow = m0 + wr * WM + mi * 16 + g * 4 + r;
                float val = acc[mi][ni][r] + bv;
                if constexpr (MODE == 0) {
                    resid[(size_t)grow * N + gcol] = val;
                } else if constexpr (MODE == 1) {
                    if constexpr (SPLITK > 1)
                        atomicAdd(&resid[(size_t)grow * N + gcol], val);
                    else
                        resid[(size_t)grow * N + gcol] += val;
                } else if constexpr (MODE == 2) {
                    float gl = 0.5f * val * (1.0f + erff(val * 0.70710678118f));
                    o0[(size_t)grow * N + gcol] = f2bf(gl);
                } else {
                    int which = gcol >> 10;
                    int cD = gcol & 1023;
                    int h = cD >> 6, d = cD & 63;
                    int b = grow / seq, s = grow % seq;
                    unsigned short* dst = (which == 0) ? o0 : ((which == 1) ? o1 : o2);
                    dst[(((size_t)(b * HH + h)) * seq + s) * 64 + d] = f2bf(val);
                }
            }
        }
    }
}

// ---------------- MFMA flash attention, QBLK=128 (8 waves) -----------------
// Q,K,V: [B,H,S,64] bf16. O: [B*Sq, Dm] bf16 (concat heads at h*64).
// Block: 128 q-rows for one (b,h). 8 waves x 16 q-rows each. K/V tiles of 64.
// S^T = mfma(K,Q) -> lane-local softmax per q-column; P packed to LDS;
// PV = mfma(P, V^T). K/V^T LDS rows XOR-swizzled ((row&7)<<4) per G4.
template<bool CAUSAL>
__global__ __launch_bounds__(512) void attn_mfma(
    const unsigned short* __restrict__ Q, const unsigned short* __restrict__ K,
    const unsigned short* __restrict__ V, unsigned short* __restrict__ O,
    const int* __restrict__ pidx, int Sq, int Sk, int Dm, float scale)
{
    __shared__ __align__(16) unsigned short Kls[64 * 64];     //  8 KB
    __shared__ __align__(16) unsigned short Vls[64 * 64];     //  8 KB (V^T)
    __shared__ __align__(16) unsigned short Pls[8 * 16 * 72]; // 18 KB

    const int b = blockIdx.z, h = blockIdx.y;
    const int nqt = Sq >> 7;
    const int bx = blockIdx.x;
    // heavy/light pairing for causal load balance
    const int qt = CAUSAL ? ((bx & 1) ? (nqt - 1 - (bx >> 1)) : (bx >> 1)) : bx;
    const int qbase = qt * 128;
    const int tid = threadIdx.x;
    const int w = tid >> 6, l = tid & 63;
    const int g = l >> 4, i16 = l & 15;
    const size_t hbase = (size_t)b * HH + h;

    const unsigned short* Qp = Q + (hbase * Sq + qbase + w * 16 + i16) * 64;
    const short8 qf0 = *(const short8*)(Qp + g * 8);
    const short8 qf1 = *(const short8*)(Qp + 32 + g * 8);

    int jm = 0;
    if (!CAUSAL) {
        int p = pidx[b * Sq + qbase + w * 16 + i16];
        jm = (p < Sk - 1) ? p : (Sk - 1);
    }

    f32x4 accO[4] = {{0,0,0,0},{0,0,0,0},{0,0,0,0},{0,0,0,0}};
    float mrun = -3.0e38f, lrun = 0.f;

    const int nkt = CAUSAL ? (2 * qt + 2) : (Sk >> 6);
    const int skr = tid >> 3;            // 0..63: K staging row
    const int sd0 = (tid & 7) * 8;       // K staging col

    for (int kt = 0; kt < nkt; ++kt) {
        const int kb = kt * 64;
        __syncthreads();
        // ---- stage K tile [64 k][64 d], 512 threads, one uint4 each ----
        const unsigned short* gK = K + (hbase * Sk + kb) * 64;
        uint4 kvv = *(const uint4*)(gK + skr * 64 + sd0);
        *(uint4*)((char*)Kls + skr * 128 + ((sd0 * 2) ^ ((skr & 7) << 4))) = kvv;
        // ---- stage V^T [d][k], each thread one short8 -> 8 u16 writes ----
        const unsigned short* gV = V + (hbase * Sk + kb) * 64;
        {
            short8 vv = *(const short8*)(gV + l * 64 + w * 8);
#pragma unroll
            for (int i = 0; i < 8; ++i) {
                int dr = w * 8 + i;
                *(unsigned short*)((char*)Vls + dr * 128 + ((l * 2) ^ ((dr & 7) << 4)))
                    = (unsigned short)vv[i];
            }
        }
        __syncthreads();

        // ---- S^T tile: rows k = kb+16t+g*4+r, col q = i16 (per wave) ----
        f32x4 accS[4] = {{0,0,0,0},{0,0,0,0},{0,0,0,0},{0,0,0,0}};
#pragma unroll
        for (int ks = 0; ks < 2; ++ks) {
            short8 qf = ks ? qf1 : qf0;
#pragma unroll
            for (int t = 0; t < 4; ++t) {
                short8 kf = *(const short8*)((char*)Kls + (16 * t + i16) * 128
                             + ((g * 16 + ks * 64) ^ ((i16 & 7) << 4)));
                accS[t] = __builtin_amdgcn_mfma_f32_16x16x32_bf16(kf, qf, accS[t], 0, 0, 0);
            }
        }

        // ---- mask + scale in place, lane-local max over q-column ----
        float mloc = -3.0e38f;
        const int qglob = qbase + w * 16 + i16;
#pragma unroll
        for (int t = 0; t < 4; ++t) {
#pragma unroll
            for (int r = 0; r < 4; ++r) {
                float x = accS[t][r] * scale;
                int kglob = kb + 16 * t + g * 4 + r;
                if (CAUSAL) { if (kglob > qglob) x = -1.0e9f; }
                else        { if (kglob > jm)    x = -1.0e9f; }
                accS[t][r] = x;
                mloc = fmaxf(mloc, x);
            }
        }
        mloc = fmaxf(mloc, __shfl_xor(mloc, 16));
        mloc = fmaxf(mloc, __shfl_xor(mloc, 32));
        float mnew = fmaxf(mrun, mloc);
        float fac = __expf(mrun - mnew);
        float psum = 0.f;
#pragma unroll
        for (int t = 0; t < 4; ++t) {
            float p0 = __expf(accS[t][0] - mnew);
            float p1 = __expf(accS[t][1] - mnew);
            float p2 = __expf(accS[t][2] - mnew);
            float p3 = __expf(accS[t][3] - mnew);
            psum += (p0 + p1) + (p2 + p3);
            uint2 u2;
            u2.x = (unsigned int)f2bf(p0) | ((unsigned int)f2bf(p1) << 16);
            u2.y = (unsigned int)f2bf(p2) | ((unsigned int)f2bf(p3) << 16);
            *(uint2*)((char*)Pls + w * 2304 + i16 * 144 + t * 32 + g * 8) = u2;
        }
        psum += __shfl_xor(psum, 16);
        psum += __shfl_xor(psum, 32);
        lrun = lrun * fac + psum;
        mrun = mnew;
        float facr0 = __shfl(fac, g * 4 + 0);
        float facr1 = __shfl(fac, g * 4 + 1);
        float facr2 = __shfl(fac, g * 4 + 2);
        float facr3 = __shfl(fac, g * 4 + 3);
#pragma unroll
        for (int t = 0; t < 4; ++t) {
            accO[t][0] *= facr0; accO[t][1] *= facr1;
            accO[t][2] *= facr2; accO[t][3] *= facr3;
        }
        // ---- PV: accO += P[q][k] * V^T ----
#pragma unroll
        for (int ks = 0; ks < 2; ++ks) {
            short8 pf = *(const short8*)((char*)Pls + w * 2304 + i16 * 144
                          + g * 16 + ks * 64);
#pragma unroll
            for (int t = 0; t < 4; ++t) {
                short8 vf = *(const short8*)((char*)Vls + (16 * t + i16) * 128
                             + ((g * 16 + ks * 64) ^ ((i16 & 7) << 4)));
                accO[t] = __builtin_amdgcn_mfma_f32_16x16x32_bf16(pf, vf, accO[t], 0, 0, 0);
            }
        }
    }

    float inv = 1.0f / lrun;
    float inv0 = __shfl(inv, g * 4 + 0);
    float inv1 = __shfl(inv, g * 4 + 1);
    float inv2 = __shfl(inv, g * 4 + 2);
    float inv3 = __shfl(inv, g * 4 + 3);
    unsigned short* Orow = O + (size_t)(b * Sq + qbase + w * 16 + g * 4) * Dm
                             + h * 64 + i16;
#pragma unroll
    for (int t = 0; t < 4; ++t) {
        Orow[t * 16]                  = f2bf(accO[t][0] * inv0);
        Orow[(size_t)Dm + t * 16]     = f2bf(accO[t][1] * inv1);
        Orow[2 * (size_t)Dm + t * 16] = f2bf(accO[t][2] * inv2);
        Orow[3 * (size_t)Dm + t * 16] = f2bf(accO[t][3] * inv3);
    }
}

// ---------------------------------------------------------------------------
extern "C" void kernel_launch(void* const* d_in, const int* in_sizes, int n_in,
                              void* d_out, int out_size, void* d_ws, size_t ws_size,
                              hipStream_t stream)
{
    (void)in_sizes; (void)n_in; (void)out_size; (void)ws_size;
    const int*   byte_seq = (const int*)d_in[0];
    const float* patch    = (const float*)d_in[1];
    const int*   pbound   = (const int*)d_in[2];
    const float* byte_emb = (const float*)d_in[3];
    const float* pos_emb  = (const float*)d_in[4];
    const float* sa_in_w  = (const float*)d_in[5];
    const float* sa_in_b  = (const float*)d_in[6];
    const float* sa_out_w = (const float*)d_in[7];
    const float* sa_out_b = (const float*)d_in[8];
    const float* ca_in_w  = (const float*)d_in[9];
    const float* ca_in_b  = (const float*)d_in[10];
    const float* ca_out_w = (const float*)d_in[11];
    const float* ca_out_b = (const float*)d_in[12];
    const float* ffn_w1   = (const float*)d_in[13];
    const float* ffn_b1   = (const float*)d_in[14];
    const float* ffn_w2   = (const float*)d_in[15];
    const float* ffn_b2   = (const float*)d_in[16];
    const float* ln_g     = (const float*)d_in[17];
    const float* ln_b     = (const float*)d_in[18];
    const float* norm_g   = (const float*)d_in[19];
    const float* norm_b   = (const float*)d_in[20];
    const float* out_w    = (const float*)d_in[21];

    char* ws = (char*)d_ws;
    float*          x   = (float*)(ws + 0);                    //  8 MB fp32 residual
    unsigned short* h   = (unsigned short*)(ws + 8388608);     //  4 MB
    unsigned short* q   = (unsigned short*)(ws + 12582912);    //  4 MB
    unsigned short* k   = (unsigned short*)(ws + 16777216);    //  4 MB
    unsigned short* v   = (unsigned short*)(ws + 20971520);    //  4 MB
    unsigned short* aO  = (unsigned short*)(ws + 25165824);    //  4 MB
    unsigned short* u   = (unsigned short*)(ws + 12582912);    // 16 MB, aliases q/k/v/aO
    unsigned short* kca = (unsigned short*)(ws + 29360128);    // 512 KB
    unsigned short* vca = (unsigned short*)(ws + 29884416);    // 512 KB
    unsigned short* pp  = (unsigned short*)(ws + 30408704);    // 512 KB patch bf16
    int*            pidx = (int*)(ws + 30932992);              //   8 KB
    unsigned short* wb  = (unsigned short*)(ws + 31457280);    // 32 MB layer weights bf16
    unsigned short* wout = (unsigned short*)(ws + 65011712);   // 512 KB out_w bf16

    embed_kernel<<<(NN * DDIM + 255) / 256, 256, 0, stream>>>(byte_seq, byte_emb, pos_emb, x);
    cvt_bf16_kernel<<<(BD * PP * DDIM + 255) / 256, 256, 0, stream>>>(patch, pp, BD * PP * DDIM);
    cvt_bf16_kernel<<<(VV * DDIM + 255) / 256, 256, 0, stream>>>(out_w, wout, VV * DDIM);
    pidx_kernel<<<1, 64, 0, stream>>>(pbound, pidx);

    unsigned short* wb_sa_in  = wb + 0;
    unsigned short* wb_sa_out = wb + 3145728;
    unsigned short* wb_ca_in  = wb + 4194304;
    unsigned short* wb_ca_kv  = wb + 4194304 + DDIM * DDIM;
    unsigned short* wb_ca_out = wb + 7340032;
    unsigned short* wb_ffn1   = wb + 8388608;
    unsigned short* wb_ffn2   = wb + 12582912;

    for (int l = 0; l < LL; ++l) {
        const float* lg = ln_g + (size_t)(l * 3) * DDIM;
        const float* lb = ln_b + (size_t)(l * 3) * DDIM;

        cvt_wts_kernel<<<16384, 256, 0, stream>>>(
            sa_in_w + (size_t)l * 3 * DDIM * DDIM, sa_out_w + (size_t)l * DDIM * DDIM,
            ca_in_w + (size_t)l * 3 * DDIM * DDIM, ca_out_w + (size_t)l * DDIM * DDIM,
            ffn_w1 + (size_t)l * 4 * DDIM * DDIM, ffn_w2 + (size_t)l * 4 * DDIM * DDIM,
            wb);

        // ---- self-attention block ----
        ln_kernel<<<NN, 256, 0, stream>>>(x, lg, lb, h);
        gemm_mfma<128, 128, 3, 1><<<dim3(3 * DDIM / 128, NN / 128), 256, 0, stream>>>(
            h, wb_sa_in, sa_in_b + (size_t)l * 3 * DDIM,
            nullptr, q, k, v, NN, 3 * DDIM, DDIM, SD);
        attn_mfma<true><<<dim3(SD / 128, HH, BD), 512, 0, stream>>>(
            q, k, v, aO, nullptr, SD, SD, DDIM, 0.125f);
        gemm_mfma<64, 128, 1, 2><<<dim3(DDIM / 128, NN / 64, 2), 256, 0, stream>>>(
            aO, wb_sa_out, sa_out_b + (size_t)l * DDIM,
            x, nullptr, nullptr, nullptr, NN, DDIM, DDIM, 0);

        // ---- cross-attention block ----
        ln_kernel<<<NN, 256, 0, stream>>>(x, lg + DDIM, lb + DDIM, h);
        gemm_mfma<64, 128, 3, 1><<<dim3(DDIM / 128, NN / 64), 256, 0, stream>>>(
            h, wb_ca_in, ca_in_b + (size_t)l * 3 * DDIM,
            nullptr, q, nullptr, nullptr, NN, DDIM, DDIM, SD);
        gemm_mfma<64, 128, 3, 1><<<dim3(2 * DDIM / 128, (BD * PP) / 64), 256, 0, stream>>>(
            pp, wb_ca_kv, ca_in_b + (size_t)l * 3 * DDIM + DDIM,
            nullptr, kca, vca, nullptr, BD * PP, 2 * DDIM, DDIM, PP);
        attn_mfma<false><<<dim3(SD / 128, HH, BD), 512, 0, stream>>>(
            q, kca, vca, aO, pidx, SD, PP, DDIM, 0.125f);
        gemm_mfma<64, 128, 1, 2><<<dim3(DDIM / 128, NN / 64, 2), 256, 0, stream>>>(
            aO, wb_ca_out, ca_out_b + (size_t)l * DDIM,
            x, nullptr, nullptr, nullptr, NN, DDIM, DDIM, 0);

        // ---- FFN block ----
        ln_kernel<<<NN, 256, 0, stream>>>(x, lg + 2 * DDIM, lb + 2 * DDIM, h);
        gemm_mfma<128, 128, 2, 1><<<dim3(4 * DDIM / 128, NN / 128), 256, 0, stream>>>(
            h, wb_ffn1, ffn_b1 + (size_t)l * 4 * DDIM,
            nullptr, u, nullptr, nullptr, NN, 4 * DDIM, DDIM, 0);
        gemm_mfma<64, 128, 1, 2><<<dim3(DDIM / 128, NN / 64, 2), 256, 0, stream>>>(
            u, wb_ffn2, ffn_b2 + (size_t)l * DDIM,
            x, nullptr, nullptr, nullptr, NN, DDIM, 4 * DDIM, 0);
    }
    ln_kernel<<<NN, 256, 0, stream>>>(x, norm_g, norm_b, h);
    gemm_mfma<64, 64, 0, 1><<<dim3(VV / 64, NN / 64), 256, 0, stream>>>(
        h, wout, nullptr, (float*)d_out, nullptr, nullptr, nullptr,
        NN, VV, DDIM, 0);
}